// Round 10
// baseline (662.406 us; speedup 1.0000x reference)
//
#include <hip/hip_runtime.h>
#include <hip/hip_bf16.h>

// Problem: B=8, L=16384, d=256, K=8, G=L/K=2048
// outputs: queries (B,L,d) f32 = 33554432 elems, final_state (B,d) = 2048 elems
#define EPSV 1e-8f

typedef __attribute__((ext_vector_type(4))) float f32x4;
typedef __attribute__((ext_vector_type(4))) unsigned short u16x4;   // renamed: ushort4 collides with HIP header
typedef __attribute__((ext_vector_type(8))) __bf16 bf16x8;
typedef __attribute__((ext_vector_type(8))) unsigned short ushort8;

static __device__ __forceinline__ unsigned short f2bf(float x) {
    __hip_bfloat16 h = __float2bfloat16(x);   // RNE
    return *reinterpret_cast<unsigned short*>(&h);
}
static __device__ __forceinline__ float bf2f(unsigned short u) {
    __hip_bfloat16 h = *reinterpret_cast<__hip_bfloat16*>(&u);
    return __bfloat162float(h);
}

// ---- VALU-only full-wave sum, LLVM AMDGPUAtomicOptimizer sequence ---------
// (verified passing in round 4)
template <int CTRL, int RMASK = 0xf>
static __device__ __forceinline__ float dpp_add(float x) {
    int y = __builtin_amdgcn_update_dpp(0, __builtin_bit_cast(int, x), CTRL, RMASK, 0xf, true);
    return x + __builtin_bit_cast(float, y);
}

static __device__ __forceinline__ float wave_allsum(float x) {
    x = dpp_add<0xB1>(x);        // quad_perm [1,0,3,2]  (xor 1)
    x = dpp_add<0x4E>(x);        // quad_perm [2,3,0,1]  (xor 2)
    x = dpp_add<0x141>(x);       // row_half_mirror      (xor 7)
    x = dpp_add<0x140>(x);       // row_mirror           (xor 15)
    x = dpp_add<0x142, 0xa>(x);  // row_bcast15 -> rows 1,3 accumulate
    x = dpp_add<0x143, 0xc>(x);  // row_bcast31 -> lane63 = total
    int t = __builtin_amdgcn_readlane(__builtin_bit_cast(int, x), 63);
    return __builtin_bit_cast(float, t);
}

// ---------------------------------------------------------------------------
// K0: build B'^T, lp folded in:  B'[n=k*256+e, d] = lp[k,d]*Wq[e,d]
// split-bf16 bands along K': [hi, lo, hi], row-major bpt[n*768 + band*256 + d]
__global__ __launch_bounds__(256) void build_bpt_kernel(const float* __restrict__ lp,
                                                        const float* __restrict__ wq,
                                                        unsigned short* __restrict__ bpt) {
    int idx = blockIdx.x * 256 + threadIdx.x;          // 2048*768 = 1,572,864 total
    int n = idx / 768;
    int j = idx - n * 768;
    int d = j & 255;
    int band = j >> 8;
    int k = n >> 8;
    int e = n & 255;
    float w = lp[k * 256 + d] * wq[e * 256 + d];
    unsigned short hi = f2bf(w);
    unsigned short v;
    if (band == 1) v = f2bf(w - bf2f(hi));             // lo
    else           v = hi;
    bpt[idx] = v;
}

// ---------------------------------------------------------------------------
// K1: per (b,g): gv = l2norm(mean_k(token[b,g,k,:]*lp[k,:]));
//     v[b,g,:] = (1-alpha) * gv * mp[g,:];  vv[b,g] = <v,v>  (for the scan)
__global__ __launch_bounds__(256) void groupvec_kernel(const float* __restrict__ tv,
                                                       const float* __restrict__ lp,
                                                       const float* __restrict__ mp,
                                                       const float* __restrict__ dl,
                                                       float* __restrict__ v,
                                                       float* __restrict__ vv) {
    int bid = blockIdx.x;              // b*2048 + g
    int g = bid & 2047;
    int d = threadIdx.x;
    const float* base = tv + (size_t)bid * 2048 + d;   // bid*8*256
    float acc = 0.f;
#pragma unroll
    for (int k = 0; k < 8; ++k)
        acc += base[k * 256] * lp[k * 256 + d];
    float m = acc * 0.125f;

    float p = m * m;
#pragma unroll
    for (int s = 1; s < 64; s <<= 1) p += __shfl_xor(p, s);
    __shared__ float red[4];
    if ((threadIdx.x & 63) == 0) red[threadIdx.x >> 6] = p;
    __syncthreads();
    float tot = red[0] + red[1] + red[2] + red[3];
    float n = sqrtf(tot);
    float inv = 1.0f / fmaxf(n, EPSV);

    float alpha = 1.0f / (1.0f + expf(-dl[d]));
    float val = (1.0f - alpha) * (m * inv) * mp[g * 256 + d];
    v[(size_t)bid * 256 + d] = val;

    // second reduce: <v,v> for the scan's scalar recurrence
    float q = val * val;
#pragma unroll
    for (int s = 1; s < 64; s <<= 1) q += __shfl_xor(q, s);
    __shared__ float red2[4];
    if ((threadIdx.x & 63) == 0) red2[threadIdx.x >> 6] = q;
    __syncthreads();
    if (threadIdx.x == 0) vv[bid] = red2[0] + red2[1] + red2[2] + red2[3];
}

// ---------------------------------------------------------------------------
// K2: sequential scan — reduction evicted from the critical path.
// ss_{g+1} = inv_g^2 * <au_g,au_g> + 2 inv_g <au_g, v_{g+1}> + <v_{g+1},v_{g+1}>
__global__ __launch_bounds__(64) void scan_kernel(const float* __restrict__ v,
                                                  const float* __restrict__ vv,
                                                  const float* __restrict__ dl,
                                                  float* __restrict__ states,
                                                  float* __restrict__ out) {
    int b = blockIdx.x;
    int lane = threadIdx.x;
    const float* vb = v + (size_t)b * 2048 * 256 + 4 * lane;
    float* sb = states + (size_t)b * 2048 * 256 + 4 * lane;
    const float* vvb = vv + b * 2048;

    f32x4 alpha;
#pragma unroll
    for (int i = 0; i < 4; ++i)
        alpha[i] = 1.0f / (1.0f + expf(-dl[4 * lane + i]));

    f32x4 buf[16];
#pragma unroll
    for (int j = 0; j < 16; ++j)
        buf[j] = *(const f32x4*)(vb + (size_t)j * 256);

    // VV window: lanes 0..15 hold vv[t + lane]
    float vvreg = (lane < 16) ? vvb[lane] : 0.f;

    f32x4 u = {0.f, 0.f, 0.f, 0.f};
    f32x4 au = {0.f, 0.f, 0.f, 0.f};   // alpha .* u_{g-1}
    f32x4 S = {0.f, 0.f, 0.f, 0.f};
    float inv = 0.f;                   // inv_{g-1}
    float ss = vvb[0];                 // ss_0 = VV_0

    for (int t = 0; t < 2048; t += 16) {
        float vvnext = 0.f;
        if (t + 16 < 2048 && lane < 16) vvnext = vvb[t + 16 + lane];
#pragma unroll
        for (int j = 0; j < 16; ++j) {
            const int g = t + j;
            f32x4 vcur = buf[j];
            if (g + 16 < 2048) buf[j] = *(const f32x4*)(vb + (size_t)(g + 16) * 256);

            // scalar head: inv_g, 1/ss_g from held ss_g
            float ssc = fmaxf(ss, 1e-16f);
            float invn = __builtin_amdgcn_rsqf(ssc);   // inv_g
            float isq = __builtin_amdgcn_rcpf(ssc);    // inv_g^2

            // u_g = inv_{g-1} * au_{g-1} + v_g   (old inv!)
            f32x4 un;
#pragma unroll
            for (int i = 0; i < 4; ++i) un[i] = fmaf(inv, au[i], vcur[i]);
            u = un;
            // au_g
#pragma unroll
            for (int i = 0; i < 4; ++i) au[i] = alpha[i] * u[i];
            // S_g = u_g * inv_g ; store
#pragma unroll
            for (int i = 0; i < 4; ++i) S[i] = u[i] * invn;
            *(f32x4*)(sb + (size_t)g * 256) = S;

            // dots on (au_g, v_{g+1}) — pipelined reduces, off the scalar path
            f32x4 vnx = buf[(j + 1) & 15];
            float pp0 = fmaf(au[1], au[1], au[0] * au[0]);
            float pp1 = fmaf(au[3], au[3], au[2] * au[2]);
            float pv0 = fmaf(au[1], vnx[1], au[0] * vnx[0]);
            float pv1 = fmaf(au[3], vnx[3], au[2] * vnx[2]);
            float PP = wave_allsum(pp0 + pp1);
            float PV = wave_allsum(pv0 + pv1);

            // VV_{g+1} from register window
            float VVn;
            if (j < 15) {
                int ti = __builtin_amdgcn_readlane(__builtin_bit_cast(int, vvreg), j + 1);
                VVn = __builtin_bit_cast(float, ti);
            } else {
                int ti = __builtin_amdgcn_readlane(__builtin_bit_cast(int, vvnext), 0);
                VVn = __builtin_bit_cast(float, ti);
            }

            // ss_{g+1} = PP*inv^2 + 2*PV*inv + VV
            float inv2 = invn + invn;
            ss = fmaf(PP, isq, fmaf(PV, inv2, VVn));
            inv = invn;
        }
        vvreg = vvnext;
    }
    // final_state: S holds S_2047 (after queries: offset 8*16384*256)
    *(f32x4*)(out + 33554432 + b * 256 + 4 * lane) = S;
}

// ---------------------------------------------------------------------------
// K2b: convert states -> row-shifted split-bf16 A.
// A row r = b*2048+g holds: g==0 ? 0 : split(states[b, g-1, :])
__global__ __launch_bounds__(256) void convert_kernel(const float* __restrict__ states,
                                                      unsigned short* __restrict__ a_hi,
                                                      unsigned short* __restrict__ a_lo) {
    int idx = blockIdx.x * 256 + threadIdx.x;   // 16384*64 = 1,048,576
    int r = idx >> 6;
    int d0 = (idx & 63) * 4;
    int g = r & 2047;
    u16x4 hi4, lo4;
    if (g == 0) {
        hi4 = (u16x4){0, 0, 0, 0};
        lo4 = (u16x4){0, 0, 0, 0};
    } else {
        f32x4 s = *(const f32x4*)(states + (size_t)(r - 1) * 256 + d0);
#pragma unroll
        for (int i = 0; i < 4; ++i) {
            unsigned short h = f2bf(s[i]);
            hi4[i] = h;
            lo4[i] = f2bf(s[i] - bf2f(h));
        }
    }
    *(u16x4*)(a_hi + (size_t)r * 256 + d0) = hi4;
    *(u16x4*)(a_lo + (size_t)r * 256 + d0) = lo4;
}

// ---------------------------------------------------------------------------
// K3: queries GEMM, restructured:  C[16384 x 2048] = A[16384 x 256] * B'^T
//   rows r=(b,g), cols n=(k,e);  out flat = r*2048 + n  (exactly queries)
// split-bf16: K' = 768, A bands [hi,hi,lo] (prebuilt), B bands [hi,lo,hi]
// BM=128, BN=256, BK=32, 8 waves (2Mx4N), wave tile 64x64
__global__ __launch_bounds__(512) void queries_gemm_kernel(const unsigned short* __restrict__ a_hi,
                                                           const unsigned short* __restrict__ a_lo,
                                                           const unsigned short* __restrict__ bpt,
                                                           float* __restrict__ out) {
    __shared__ unsigned short As[128 * 40];   // pitch 40 bf16 (80B)
    __shared__ unsigned short Bs[256 * 40];

    int tid = threadIdx.x;
    int lane = tid & 63;
    int wid = tid >> 6;
    int wm = wid >> 2;          // 0..1
    int wn = wid & 3;           // 0..3
    int row0 = (blockIdx.x >> 3) * 128;
    int col0 = (blockIdx.x & 7) * 256;

    f32x4 acc[4][4];
#pragma unroll
    for (int i = 0; i < 4; ++i)
#pragma unroll
        for (int j = 0; j < 4; ++j) acc[i][j] = (f32x4){0.f, 0.f, 0.f, 0.f};

    int ar = tid >> 2;                   // 0..127
    int aj0 = (tid & 3) * 8;             // 0,8,16,24
    int be = tid >> 1;                   // 0..255
    int bj0 = (tid & 1) * 16;            // 0 or 16

    const size_t arow_off = (size_t)(row0 + ar) * 256;
    const size_t brow_off = (size_t)(col0 + be) * 768;

    for (int c = 0; c < 24; ++c) {
        int kc = c * 32;
        int band = c >> 3;               // 0,1 -> A hi ; 2 -> A lo
        int dc = (c & 7) * 32;

        // ---- stage A: plain 16B bf16 copy from prebuilt band
        {
            const unsigned short* Ab = (band < 2) ? a_hi : a_lo;
            ushort8 h = *(const ushort8*)(Ab + arow_off + dc + aj0);
            *(ushort8*)&As[ar * 40 + aj0] = h;
        }
        // ---- stage B: plain 32B copy
        {
            const unsigned short* src = bpt + brow_off + kc + bj0;
            ushort8 b0 = *(const ushort8*)src;
            ushort8 b1 = *(const ushort8*)(src + 8);
            *(ushort8*)&Bs[be * 40 + bj0] = b0;
            *(ushort8*)&Bs[be * 40 + bj0 + 8] = b1;
        }
        __syncthreads();

        // ---- fragments + MFMA
        int lr = lane & 15;
        int lk = (lane >> 4) * 8;
        bf16x8 af[4], bfr[4];
#pragma unroll
        for (int mi = 0; mi < 4; ++mi) {
            ushort8 r = *(const ushort8*)&As[(wm * 64 + mi * 16 + lr) * 40 + lk];
            af[mi] = __builtin_bit_cast(bf16x8, r);
        }
#pragma unroll
        for (int ni = 0; ni < 4; ++ni) {
            ushort8 r = *(const ushort8*)&Bs[(wn * 64 + ni * 16 + lr) * 40 + lk];
            bfr[ni] = __builtin_bit_cast(bf16x8, r);
        }
#pragma unroll
        for (int mi = 0; mi < 4; ++mi)
#pragma unroll
            for (int ni = 0; ni < 4; ++ni)
                acc[mi][ni] = __builtin_amdgcn_mfma_f32_16x16x32_bf16(af[mi], bfr[ni], acc[mi][ni], 0, 0, 0);
        __syncthreads();
    }

    // ---- epilogue: C row=(lane>>4)*4+q, col=lane&15
    int cr = (lane >> 4) * 4;
    int cc = lane & 15;
#pragma unroll
    for (int mi = 0; mi < 4; ++mi) {
#pragma unroll
        for (int ni = 0; ni < 4; ++ni) {
            int Rg = row0 + wm * 64 + mi * 16 + cr;
            int E = col0 + wn * 64 + ni * 16 + cc;
#pragma unroll
            for (int q = 0; q < 4; ++q)
                out[(size_t)(Rg + q) * 2048 + E] = acc[mi][ni][q];
        }
    }
}

// ---------------------------------------------------------------------------
extern "C" void kernel_launch(void* const* d_in, const int* in_sizes, int n_in,
                              void* d_out, int out_size, void* d_ws, size_t ws_size,
                              hipStream_t stream) {
    const float* tv = (const float*)d_in[0];   // token_vectors (8,16384,256)
    const float* lp = (const float*)d_in[1];   // local_positions (8,256)
    const float* mp = (const float*)d_in[2];   // macro_positions (2048,256)
    const float* dl = (const float*)d_in[3];   // decay_logit (256)
    const float* wq = (const float*)d_in[4];   // W_q (256,256)
    float* out = (float*)d_out;

    // workspace layout (~35.1 MB):
    float* v = (float*)d_ws;                               // 16 MB (reused as A after scan)
    float* states = v + 4194304;                           // 16 MB
    unsigned short* bpt = (unsigned short*)(states + 4194304); // 2048*768 bf16 = 3 MB
    float* vv = (float*)(bpt + 1572864);                   // 16384 f32 = 64 KB
    // A buffers overlay v (v is dead after scan_kernel):
    unsigned short* a_hi = (unsigned short*)v;             // 8 MB
    unsigned short* a_lo = a_hi + 4194304;                 // 8 MB

    build_bpt_kernel<<<6144, 256, 0, stream>>>(lp, wq, bpt);
    groupvec_kernel<<<16384, 256, 0, stream>>>(tv, lp, mp, dl, v, vv);
    scan_kernel<<<8, 64, 0, stream>>>(v, vv, dl, states, out);
    convert_kernel<<<4096, 256, 0, stream>>>(states, a_hi, a_lo);
    queries_gemm_kernel<<<1024, 512, 0, stream>>>(a_hi, a_lo, bpt, out);
}